// Round 3
// baseline (539.886 us; speedup 1.0000x reference)
//
#include <hip/hip_runtime.h>
#include <hip/hip_bf16.h>

// ---------------------------------------------------------------------------
// SelfAttention: y = proj(attn(qkv(x)))   B=4 T=2048 C=1024 H=16 HD=64
// Inputs/outputs are FLOAT32 (per reference); pad_mask is int32.
// Internally: convert to bf16, MFMA 16x16x32 bf16, accumulate f32.
// ---------------------------------------------------------------------------

using short8  = __attribute__((ext_vector_type(8))) short;
using float4_ = __attribute__((ext_vector_type(4))) float;

#define Bb   4
#define Tt   2048
#define Cc   1024
#define Hh   16
#define HDd  64

__device__ __forceinline__ float bf2f(unsigned short u) {
    union { float f; unsigned int i; } x; x.i = ((unsigned int)u) << 16; return x.f;
}
__device__ __forceinline__ unsigned short f2bf(float f) {
    union { float f; unsigned int i; } x; x.f = f;
    unsigned int r = x.i + 0x7fff + ((x.i >> 16) & 1);
    return (unsigned short)(r >> 16);
}

// ---------------------------------------------------------------------------
// Transpose + convert: in f32 [R][Ccols] -> out bf16 [Ccols][R]
// ---------------------------------------------------------------------------
__global__ __launch_bounds__(256) void transpose_f32_bf16(
    const float* __restrict__ in, unsigned short* __restrict__ out,
    int R, int Ccols)
{
    __shared__ unsigned short tile[32][33];
    int c0 = blockIdx.x * 32, r0 = blockIdx.y * 32;
    int tx = threadIdx.x & 31, ty = threadIdx.x >> 5;   // ty 0..7
    for (int o = 0; o < 32; o += 8)
        tile[ty + o][tx] = f2bf(in[(size_t)(r0 + ty + o) * Ccols + c0 + tx]);
    __syncthreads();
    for (int o = 0; o < 32; o += 8)
        out[(size_t)(c0 + ty + o) * R + r0 + tx] = tile[tx][ty + o];
}

// ---------------------------------------------------------------------------
// GEMM: C = A[M][K](f32) * Bt[N][K](bf16)^T
// 64x64 block tile, BK=32, 4 waves each computing 32x32 via 2x2 MFMA 16x16x32.
// MFMA 16x16x32 bf16 layouts:
//   A-frag : lane holds A[m=lane&15][k=(lane>>4)*8 + j], j=0..7
//   B-frag : lane holds B[k=(lane>>4)*8 + j][n=lane&15]
//   C/D    : lane reg r holds C[row=(lane>>4)*4+r][col=lane&15]
// ---------------------------------------------------------------------------
#define BM  64
#define BN  64
#define BK  32
#define LDA 40   // padded LDS row stride (elems): 80B, 16B-aligned

__device__ __forceinline__ short8 ld_cvt8(const float* p) {
    float4_ f0 = *(const float4_*)p;
    float4_ f1 = *(const float4_*)(p + 4);
    short8 h;
    h[0] = (short)f2bf(f0[0]); h[1] = (short)f2bf(f0[1]);
    h[2] = (short)f2bf(f0[2]); h[3] = (short)f2bf(f0[3]);
    h[4] = (short)f2bf(f1[0]); h[5] = (short)f2bf(f1[1]);
    h[6] = (short)f2bf(f1[2]); h[7] = (short)f2bf(f1[3]);
    return h;
}

__global__ __launch_bounds__(256) void gemm_qkv(
    const float* __restrict__ A,            // x: [8192][1024] f32
    const unsigned short* __restrict__ Bt,  // w_attn^T: [3072][1024] bf16
    unsigned short* __restrict__ Q,         // [B][H][T][HD] bf16
    unsigned short* __restrict__ Ko,
    unsigned short* __restrict__ V)
{
    __shared__ unsigned short As[BM * LDA];
    __shared__ unsigned short Bs[BN * LDA];
    const int K = 1024;
    int m0 = blockIdx.x * BM;
    int n0 = blockIdx.y * BN;
    int tid  = threadIdx.x;
    int wave = tid >> 6, lane = tid & 63;
    int wm = (wave >> 1) * 32, wn = (wave & 1) * 32;
    int lr = lane & 15, lk = (lane >> 4) * 8;
    int sr = tid >> 2, sc = (tid & 3) * 8;

    float4_ acc[2][2] = {};
    for (int k0 = 0; k0 < K; k0 += BK) {
        *(short8*)&As[sr * LDA + sc] = ld_cvt8(&A[(size_t)(m0 + sr) * K + k0 + sc]);
        *(short8*)&Bs[sr * LDA + sc] = *(const short8*)&Bt[(size_t)(n0 + sr) * K + k0 + sc];
        __syncthreads();
        short8 a0 = *(short8*)&As[(wm +      lr) * LDA + lk];
        short8 a1 = *(short8*)&As[(wm + 16 + lr) * LDA + lk];
        short8 b0 = *(short8*)&Bs[(wn +      lr) * LDA + lk];
        short8 b1 = *(short8*)&Bs[(wn + 16 + lr) * LDA + lk];
        acc[0][0] = __builtin_amdgcn_mfma_f32_16x16x32_bf16(a0, b0, acc[0][0], 0, 0, 0);
        acc[0][1] = __builtin_amdgcn_mfma_f32_16x16x32_bf16(a0, b1, acc[0][1], 0, 0, 0);
        acc[1][0] = __builtin_amdgcn_mfma_f32_16x16x32_bf16(a1, b0, acc[1][0], 0, 0, 0);
        acc[1][1] = __builtin_amdgcn_mfma_f32_16x16x32_bf16(a1, b1, acc[1][1], 0, 0, 0);
        __syncthreads();
    }
    // epilogue: scatter into head-major Q/K/V (bf16)
    for (int i = 0; i < 2; i++)
        for (int j = 0; j < 2; j++) {
            int n = n0 + wn + 16 * j + lr;
            int which = n >> 10;
            int c = n & 1023;
            int h = c >> 6, d = c & 63;
            unsigned short* dst = (which == 0) ? Q : ((which == 1) ? Ko : V);
            for (int r = 0; r < 4; r++) {
                int m = m0 + wm + 16 * i + (lane >> 4) * 4 + r;
                int b = m >> 11, t = m & 2047;
                dst[(((size_t)(b * Hh + h) * Tt) + t) * HDd + d] = f2bf(acc[i][j][r]);
            }
        }
}

__global__ __launch_bounds__(256) void gemm_proj(
    const unsigned short* __restrict__ A,   // y: [8192][1024] bf16
    const unsigned short* __restrict__ Bt,  // w_proj^T: [1024][1024] bf16
    const float* __restrict__ bias,         // [1024] f32
    float* __restrict__ Out)                // [8192][1024] f32
{
    __shared__ unsigned short As[BM * LDA];
    __shared__ unsigned short Bs[BN * LDA];
    const int K = 1024;
    int m0 = blockIdx.x * BM;
    int n0 = blockIdx.y * BN;
    int tid  = threadIdx.x;
    int wave = tid >> 6, lane = tid & 63;
    int wm = (wave >> 1) * 32, wn = (wave & 1) * 32;
    int lr = lane & 15, lk = (lane >> 4) * 8;
    int sr = tid >> 2, sc = (tid & 3) * 8;

    float4_ acc[2][2] = {};
    for (int k0 = 0; k0 < K; k0 += BK) {
        *(short8*)&As[sr * LDA + sc] = *(const short8*)&A [(size_t)(m0 + sr) * K + k0 + sc];
        *(short8*)&Bs[sr * LDA + sc] = *(const short8*)&Bt[(size_t)(n0 + sr) * K + k0 + sc];
        __syncthreads();
        short8 a0 = *(short8*)&As[(wm +      lr) * LDA + lk];
        short8 a1 = *(short8*)&As[(wm + 16 + lr) * LDA + lk];
        short8 b0 = *(short8*)&Bs[(wn +      lr) * LDA + lk];
        short8 b1 = *(short8*)&Bs[(wn + 16 + lr) * LDA + lk];
        acc[0][0] = __builtin_amdgcn_mfma_f32_16x16x32_bf16(a0, b0, acc[0][0], 0, 0, 0);
        acc[0][1] = __builtin_amdgcn_mfma_f32_16x16x32_bf16(a0, b1, acc[0][1], 0, 0, 0);
        acc[1][0] = __builtin_amdgcn_mfma_f32_16x16x32_bf16(a1, b0, acc[1][0], 0, 0, 0);
        acc[1][1] = __builtin_amdgcn_mfma_f32_16x16x32_bf16(a1, b1, acc[1][1], 0, 0, 0);
        __syncthreads();
    }
    for (int i = 0; i < 2; i++)
        for (int j = 0; j < 2; j++) {
            int n = n0 + wn + 16 * j + lr;
            float bv = bias[n];
            for (int r = 0; r < 4; r++) {
                int m = m0 + wm + 16 * i + (lane >> 4) * 4 + r;
                Out[(size_t)m * 1024 + n] = acc[i][j][r] + bv;
            }
        }
}

// ---------------------------------------------------------------------------
// Flash attention (causal + key pad mask). All bf16 in, bf16 out, f32 accum.
// Block = 4 waves; block handles (b,h) and 64 q rows (16 per wave).
// ---------------------------------------------------------------------------
#define DPAD 72   // padded row stride (elems) = 144B

__global__ __launch_bounds__(256) void attn_fwd(
    const unsigned short* __restrict__ Q,   // [B][H][T][HD]
    const unsigned short* __restrict__ Kg,
    const unsigned short* __restrict__ Vg,
    const int* __restrict__ pad,            // [B][T]
    unsigned short* __restrict__ Y)         // [B][T][C]
{
    __shared__ unsigned short Kt[64 * DPAD];      // [key][d]
    __shared__ unsigned short Vt[64 * DPAD];      // [d][key]
    __shared__ unsigned short Pl[4 * 16 * DPAD];  // per-wave [qrow][key]

    int qb = blockIdx.x;            // 0..31 (q tile of 64)
    int bh = blockIdx.y;            // 0..63
    int b  = bh >> 4, h = bh & 15;
    const size_t base = (size_t)bh * Tt * HDd;
    int tid  = threadIdx.x;
    int wave = tid >> 6, lane = tid & 63;
    int lr = lane & 15, lg = lane >> 4;
    int q0 = qb * 64 + wave * 16;
    unsigned short* Pw = &Pl[wave * 16 * DPAD];

    short8 qf0 = *(const short8*)&Q[base + (size_t)(q0 + lr) * HDd + lg * 8];
    short8 qf1 = *(const short8*)&Q[base + (size_t)(q0 + lr) * HDd + 32 + lg * 8];

    float m_i[4], l_i[4];
    float4_ o_acc[4];
    for (int r = 0; r < 4; r++) { m_i[r] = -1e30f; l_i[r] = 0.f; }
    for (int dt = 0; dt < 4; dt++) o_acc[dt] = (float4_){0.f, 0.f, 0.f, 0.f};

    const float scale = 0.125f;   // 1/sqrt(64)
    int nkt = qb + 1;
    for (int kt = 0; kt < nkt; kt++) {
        int k0 = kt * 64;
        // stage K (as-is) and V (transposed); 64x64 tile in two 32-col halves
        {
            int r = tid >> 2, cbase = (tid & 3) * 8;
            #pragma unroll
            for (int half = 0; half < 2; half++) {
                int c = cbase + half * 32;
                *(short8*)&Kt[r * DPAD + c] =
                    *(const short8*)&Kg[base + (size_t)(k0 + r) * HDd + c];
                alignas(16) unsigned short tmp[8];
                *(short8*)tmp = *(const short8*)&Vg[base + (size_t)(k0 + r) * HDd + c];
                for (int j = 0; j < 8; j++)
                    Vt[(c + j) * DPAD + r] = tmp[j];
            }
        }
        __syncthreads();

        // S = Q K^T * scale, causal + pad mask
        float4_ s[4];
        for (int nt = 0; nt < 4; nt++) {
            short8 kf0 = *(short8*)&Kt[(nt * 16 + lr) * DPAD + lg * 8];
            short8 kf1 = *(short8*)&Kt[(nt * 16 + lr) * DPAD + 32 + lg * 8];
            float4_ a = (float4_){0.f, 0.f, 0.f, 0.f};
            a = __builtin_amdgcn_mfma_f32_16x16x32_bf16(qf0, kf0, a, 0, 0, 0);
            a = __builtin_amdgcn_mfma_f32_16x16x32_bf16(qf1, kf1, a, 0, 0, 0);
            s[nt] = a;
        }
        for (int nt = 0; nt < 4; nt++) {
            int key = k0 + nt * 16 + lr;
            bool keep_k = pad[b * Tt + key] != 0;
            for (int r = 0; r < 4; r++) {
                int qrow = q0 + lg * 4 + r;
                float sv = s[nt][r] * scale;
                if (!keep_k || key > qrow) sv = -1e30f;
                s[nt][r] = sv;
            }
        }
        // online softmax
        float mn[4], alpha[4];
        for (int r = 0; r < 4; r++) {
            float v = fmaxf(fmaxf(s[0][r], s[1][r]), fmaxf(s[2][r], s[3][r]));
            for (int off = 1; off < 16; off <<= 1)
                v = fmaxf(v, __shfl_xor(v, off, 64));
            float m_new = fmaxf(m_i[r], v);
            alpha[r] = __expf(m_i[r] - m_new);
            mn[r] = m_new;
        }
        float rsum[4] = {0.f, 0.f, 0.f, 0.f};
        for (int nt = 0; nt < 4; nt++)
            for (int r = 0; r < 4; r++) {
                float p = __expf(s[nt][r] - mn[r]);
                s[nt][r] = p;
                rsum[r] += p;
            }
        for (int r = 0; r < 4; r++) {
            float v = rsum[r];
            for (int off = 1; off < 16; off <<= 1)
                v += __shfl_xor(v, off, 64);
            l_i[r] = l_i[r] * alpha[r] + v;
            m_i[r] = mn[r];
        }
        // P: C-layout regs -> wave-private LDS (A-layout source)
        for (int nt = 0; nt < 4; nt++)
            for (int r = 0; r < 4; r++)
                Pw[(lg * 4 + r) * DPAD + nt * 16 + lr] = f2bf(s[nt][r]);
        for (int dt = 0; dt < 4; dt++)
            for (int r = 0; r < 4; r++)
                o_acc[dt][r] *= alpha[r];
        // O += P @ V
        short8 pf0 = *(short8*)&Pw[lr * DPAD + lg * 8];
        short8 pf1 = *(short8*)&Pw[lr * DPAD + 32 + lg * 8];
        for (int dt = 0; dt < 4; dt++) {
            short8 vf0 = *(short8*)&Vt[(dt * 16 + lr) * DPAD + lg * 8];
            short8 vf1 = *(short8*)&Vt[(dt * 16 + lr) * DPAD + 32 + lg * 8];
            o_acc[dt] = __builtin_amdgcn_mfma_f32_16x16x32_bf16(pf0, vf0, o_acc[dt], 0, 0, 0);
            o_acc[dt] = __builtin_amdgcn_mfma_f32_16x16x32_bf16(pf1, vf1, o_acc[dt], 0, 0, 0);
        }
        __syncthreads();
    }
    // epilogue: Y[b][t][h*64+d] = O / l  (bf16)
    for (int dt = 0; dt < 4; dt++)
        for (int r = 0; r < 4; r++) {
            int qrow = q0 + lg * 4 + r;
            float o = o_acc[dt][r] / l_i[r];
            Y[((size_t)b * Tt + qrow) * Cc + h * HDd + dt * 16 + lr] = f2bf(o);
        }
}

// ---------------------------------------------------------------------------
extern "C" void kernel_launch(void* const* d_in, const int* in_sizes, int n_in,
                              void* d_out, int out_size, void* d_ws, size_t ws_size,
                              hipStream_t stream)
{
    const float* x      = (const float*)d_in[0];
    const int*   pad    = (const int*)d_in[1];
    const float* w_attn = (const float*)d_in[2];
    const float* w_proj = (const float*)d_in[3];
    const float* b_proj = (const float*)d_in[4];
    float*       out    = (float*)d_out;

    // workspace carve-up (bf16 elems)
    unsigned short* Wta = (unsigned short*)d_ws;            // 3072*1024
    unsigned short* Wtp = Wta + (size_t)3072 * 1024;        // 1024*1024
    unsigned short* Qb  = Wtp + (size_t)1024 * 1024;
    unsigned short* Kb  = Qb + (size_t)Bb * Hh * Tt * HDd;
    unsigned short* Vb  = Kb + (size_t)Bb * Hh * Tt * HDd;
    unsigned short* Yb  = Vb + (size_t)Bb * Hh * Tt * HDd;

    // 1) transpose+convert weights to bf16 [N][K]
    transpose_f32_bf16<<<dim3(3072 / 32, 1024 / 32), 256, 0, stream>>>(w_attn, Wta, 1024, 3072);
    transpose_f32_bf16<<<dim3(1024 / 32, 1024 / 32), 256, 0, stream>>>(w_proj, Wtp, 1024, 1024);
    // 2) qkv = x @ w_attn, scattered to head-major Q/K/V (bf16)
    gemm_qkv<<<dim3(8192 / BM, 3072 / BN), 256, 0, stream>>>(x, Wta, Qb, Kb, Vb);
    // 3) flash attention
    attn_fwd<<<dim3(Tt / 64, Bb * Hh), 256, 0, stream>>>(Qb, Kb, Vb, pad, Yb);
    // 4) out = y @ w_proj + b_proj (f32 out)
    gemm_proj<<<dim3(8192 / BM, 1024 / BN), 256, 0, stream>>>(Yb, Wtp, b_proj, out);
}